// Round 4
// baseline (191.608 us; speedup 1.0000x reference)
//
#include <hip/hip_runtime.h>
#include <hip/hip_bf16.h>

// DynamicPatching: B=32, C=64, T=8192, S=64 segments per batch.
// out[b,s,c,p] = (p < end[b,s]-start[b,s]) ? tensor[b,c,start[b,s]+p] : 0
// Output shape (B, S, C, max_length) float32. Measured max_length == 256.
//
// R1: 131k tiny blocks, 1 elem/thread -> latency-bound, 98 us.
// R2: block per (b,s), float4 stores, clamped always-load -> ~60 us, but
//     over-reads 2x (loads all 256 positions, selects).
// R3: nontemporal builtin rejects HIP float4 (struct); use clang ext_vector.
// R4: predicated loads (only p < len -> in-bounds by construction, no clamp),
//     non-temporal 16B stores (out is write-once; don't evict tensor from
//     L2/L3). Read demand 134 MB -> 64 MB.

#define DP_B 32
#define DP_C 64
#define DP_T 8192
#define DP_S 64

typedef float vfloat4 __attribute__((ext_vector_type(4)));

// Fast path: L == 256 (L/4 == 64 float4 per row).
template <int L>
__global__ __launch_bounds__(256) void dp_kernel_fixed(
    const float* __restrict__ tensor,      // (B, C, T)
    const int* __restrict__ change_points, // (B, S+1)
    float* __restrict__ out) {             // (B, S, C, L)
  static_assert(L % 4 == 0, "L must be /4");
  const int bs = blockIdx.x;  // b*S + s
  const int b = bs >> 6;      // S == 64
  const int start = change_points[b * (DP_S + 1) + (bs & 63)];
  const int len = change_points[b * (DP_S + 1) + (bs & 63) + 1] - start;

  const float* __restrict__ bbase = tensor + (size_t)b * DP_C * DP_T + start;
  float* __restrict__ dst = out + (size_t)bs * DP_C * L;

  constexpr int QPR = L / 4;        // float4 quads per row
  constexpr int NV = DP_C * QPR;    // float4 units per block tile
#pragma unroll 4
  for (int v = threadIdx.x; v < NV; v += 256) {
    const int c = v / QPR;
    const int p = (v % QPR) * 4;
    const float* __restrict__ row = bbase + (size_t)c * DP_T;
    vfloat4 val = {0.0f, 0.0f, 0.0f, 0.0f};
    if (p + 3 < len) {
      // Full quad in-segment: 4 unconditional in-bounds loads.
      val.x = row[p + 0];
      val.y = row[p + 1];
      val.z = row[p + 2];
      val.w = row[p + 3];
    } else if (p < len) {
      // Boundary quad (at most one lane per row).
      val.x = row[p];
      if (p + 1 < len) val.y = row[p + 1];
      if (p + 2 < len) val.z = row[p + 2];
    }
    __builtin_nontemporal_store(val, (vfloat4*)(dst + v * 4));
  }
}

// Generic fallback (any max_len): scalar, one block per (b,s,c) row.
__global__ __launch_bounds__(256) void dp_kernel_generic(
    const float* __restrict__ tensor,
    const int* __restrict__ change_points,
    float* __restrict__ out, int max_len) {
  const int c = blockIdx.x;
  const int bs = blockIdx.y;
  const int b = bs >> 6;
  const int s = bs & 63;
  const int start = change_points[b * (DP_S + 1) + s];
  const int len = change_points[b * (DP_S + 1) + s + 1] - start;
  const float* __restrict__ src = tensor + ((size_t)b * DP_C + c) * DP_T;
  float* __restrict__ dst = out + ((size_t)bs * DP_C + c) * (size_t)max_len;
  for (int p = threadIdx.x; p < max_len; p += blockDim.x) {
    float t = 0.0f;
    if (p < len) t = src[start + p];
    dst[p] = t;
  }
}

extern "C" void kernel_launch(void* const* d_in, const int* in_sizes, int n_in,
                              void* d_out, int out_size, void* d_ws, size_t ws_size,
                              hipStream_t stream) {
  const float* tensor = (const float*)d_in[0];
  const int* change_points = (const int*)d_in[1];
  const int max_len = out_size / (DP_B * DP_S * DP_C);
  float* out = (float*)d_out;

  if (max_len == 256) {
    dp_kernel_fixed<256><<<dim3(DP_B * DP_S), dim3(256), 0, stream>>>(
        tensor, change_points, out);
  } else {
    dp_kernel_generic<<<dim3(DP_C, DP_B * DP_S), dim3(256), 0, stream>>>(
        tensor, change_points, out, max_len);
  }
}

// Round 5
// 189.222 us; speedup vs baseline: 1.0126x; 1.0126x over previous
//
#include <hip/hip_runtime.h>
#include <hip/hip_bf16.h>

// DynamicPatching: B=32, C=64, T=8192, S=64 segments per batch.
// out[b,s,c,p] = (p < end[b,s]-start[b,s]) ? tensor[b,c,start[b,s]+p] : 0
// Output shape (B, S, C, max_length) float32. Measured max_length == 256.
//
// R1: 131k tiny blocks -> latency-bound, 98 us.
// R2: block/(b,s), float4 stores, clamped scalar loads -> ~60 us.
// R4: predicated loads + nt stores -> NEUTRAL (~60 us). Bytes halved but the
//     per-instruction address divergence (stride-16B scalar loads, 16 lines
//     per instr) did not change -> VMEM line-transaction bound, not BW bound.
// R5: one wave per row; lane j loads ALIGNED quad (start>>2)+j (contiguous
//     1KB per load instr), funnel-realign via __shfl_down by (start&3)
//     (wave-uniform switch), masked, one float4 nt store. 1 load + 1 store
//     instruction per row instead of 5, all fully coalesced.

#define DP_B 32
#define DP_C 64
#define DP_T 8192
#define DP_S 64

typedef float vfloat4 __attribute__((ext_vector_type(4)));

// Fast path: L == 256 (exactly 64 float4 per row == one wave).
template <int L>
__global__ __launch_bounds__(256) void dp_kernel_align(
    const float* __restrict__ tensor,      // (B, C, T)
    const int* __restrict__ change_points, // (B, S+1)
    float* __restrict__ out) {             // (B, S, C, L)
  static_assert(L == 256, "one wave per row");
  const int bs = blockIdx.x;  // b*S + s
  const int b = bs >> 6;      // S == 64
  const int start = change_points[b * (DP_S + 1) + (bs & 63)];
  const int end   = change_points[b * (DP_S + 1) + (bs & 63) + 1];
  const int len = end - start;

  const int a = start & 3;        // word misalignment within a quad
  const int base_q = start >> 2;  // first aligned quad index
  // Last aligned-quad offset (relative to base_q) containing a valid word.
  const int jmax = (len > 0) ? (((end - 1) >> 2) - base_q) : -1;

  const int lane = threadIdx.x & 63;
  const int wave = threadIdx.x >> 6;  // 0..3

  const float* __restrict__ brow = tensor + (size_t)b * DP_C * DP_T;
  float* __restrict__ dstb = out + (size_t)bs * DP_C * L;

  const int p = lane * 4;  // output word base for this lane

  for (int c = wave; c < DP_C; c += 4) {
    // 16B-aligned source base for this row's window.
    const float* __restrict__ arow = brow + (size_t)c * DP_T + (size_t)base_q * 4;

    vfloat4 q = {0.0f, 0.0f, 0.0f, 0.0f};
    if (lane <= jmax) q = *(const vfloat4*)(arow + (size_t)lane * 4);

    vfloat4 val;
    if (a == 0) {
      val = q;  // already aligned; no cross-lane traffic (25% of blocks)
    } else {
      vfloat4 nxt;
      nxt.x = __shfl_down(q.x, 1);
      nxt.y = __shfl_down(q.y, 1);
      nxt.z = __shfl_down(q.z, 1);
      nxt.w = __shfl_down(q.w, 1);
      if (lane == 63 && jmax >= 64)
        nxt = *(const vfloat4*)(arow + 64 * 4);
      // out word k = src word (a + k) within the 8-word [q,nxt] window.
      switch (a) {  // wave-uniform branch
        case 1: val.x = q.y; val.y = q.z; val.z = q.w; val.w = nxt.x; break;
        case 2: val.x = q.z; val.y = q.w; val.z = nxt.x; val.w = nxt.y; break;
        default: val.x = q.w; val.y = nxt.x; val.z = nxt.y; val.w = nxt.z; break;
      }
    }

    val.x = (p + 0 < len) ? val.x : 0.0f;
    val.y = (p + 1 < len) ? val.y : 0.0f;
    val.z = (p + 2 < len) ? val.z : 0.0f;
    val.w = (p + 3 < len) ? val.w : 0.0f;

    __builtin_nontemporal_store(val, (vfloat4*)(dstb + (size_t)c * L + p));
  }
}

// Generic fallback (any max_len): scalar, one block per (b,s,c) row.
__global__ __launch_bounds__(256) void dp_kernel_generic(
    const float* __restrict__ tensor,
    const int* __restrict__ change_points,
    float* __restrict__ out, int max_len) {
  const int c = blockIdx.x;
  const int bs = blockIdx.y;
  const int b = bs >> 6;
  const int s = bs & 63;
  const int start = change_points[b * (DP_S + 1) + s];
  const int len = change_points[b * (DP_S + 1) + s + 1] - start;
  const float* __restrict__ src = tensor + ((size_t)b * DP_C + c) * DP_T;
  float* __restrict__ dst = out + ((size_t)bs * DP_C + c) * (size_t)max_len;
  for (int p = threadIdx.x; p < max_len; p += blockDim.x) {
    float t = 0.0f;
    if (p < len) t = src[start + p];
    dst[p] = t;
  }
}

extern "C" void kernel_launch(void* const* d_in, const int* in_sizes, int n_in,
                              void* d_out, int out_size, void* d_ws, size_t ws_size,
                              hipStream_t stream) {
  const float* tensor = (const float*)d_in[0];
  const int* change_points = (const int*)d_in[1];
  const int max_len = out_size / (DP_B * DP_S * DP_C);
  float* out = (float*)d_out;

  if (max_len == 256) {
    dp_kernel_align<256><<<dim3(DP_B * DP_S), dim3(256), 0, stream>>>(
        tensor, change_points, out);
  } else {
    dp_kernel_generic<<<dim3(DP_C, DP_B * DP_S), dim3(256), 0, stream>>>(
        tensor, change_points, out, max_len);
  }
}

// Round 6
// 185.860 us; speedup vs baseline: 1.0309x; 1.0181x over previous
//
#include <hip/hip_runtime.h>
#include <hip/hip_bf16.h>

// DynamicPatching: B=32, C=64, T=8192, S=64 segments per batch.
// out[b,s,c,p] = (p < end[b,s]-start[b,s]) ? tensor[b,c,start[b,s]+p] : 0
// Output shape (B, S, C, max_length) float32. Measured max_length == 256.
//
// R1: 131k tiny blocks -> latency-bound, 98 us.
// R2/R4: block per (b,s), float4 stores, scalar loads -> ~60 us (neutral pair).
// R5: wave per row, aligned-quad load + shfl realign, 16-iter c-loop -> 57 us.
//     Three different structures all ~57-60 us => latency/parallelism wall:
//     2048 blocks x 1 outstanding load/wave is too little in-flight traffic.
// R6: fully flat: ONE THREAD PER OUTPUT FLOAT4 (32768 blocks, no loop).
//     Wave's 64 lanes = one row's 64 quads, so the realign trick keeps
//     working: 1 aligned 16B load + shfl_down realign + 1 nt 16B store.
//     Output word offset == tid*4 exactly.

#define DP_B 32
#define DP_C 64
#define DP_T 8192
#define DP_S 64

typedef float vfloat4 __attribute__((ext_vector_type(4)));

// Fast path: L == 256 (one wave == one (b,s,c) row of 64 float4 quads).
__global__ __launch_bounds__(256) void dp_kernel_flat(
    const float* __restrict__ tensor,      // (B, C, T)
    const int* __restrict__ change_points, // (B, S+1)
    float* __restrict__ out) {             // (B, S, C, 256)
  const int tid  = blockIdx.x * 256 + threadIdx.x;
  const int lane = threadIdx.x & 63;
  const int row  = tid >> 6;   // bs*64 + c  (wave-uniform)
  const int c    = row & 63;
  const int bs   = row >> 6;
  const int b    = bs >> 6;
  const int s    = bs & 63;

  // Wave-uniform segment descriptor (compiler scalarizes these loads).
  const int start = change_points[b * (DP_S + 1) + s];
  const int end   = change_points[b * (DP_S + 1) + s + 1];
  const int len   = end - start;
  const int a      = start & 3;   // word misalignment within a quad
  const int base_q = start >> 2;  // first aligned quad
  const int jmax   = ((end - 1) >> 2) - base_q;  // last valid aligned quad

  const float* __restrict__ arow =
      tensor + ((size_t)b * DP_C + c) * DP_T + (size_t)base_q * 4;

  vfloat4 q = {0.0f, 0.0f, 0.0f, 0.0f};
  if (lane <= jmax) q = *(const vfloat4*)(arow + (size_t)lane * 4);

  vfloat4 val;
  if (a == 0) {
    val = q;  // aligned segment: no cross-lane traffic (~25% of rows)
  } else {
    vfloat4 nxt;
    nxt.x = __shfl_down(q.x, 1);
    nxt.y = __shfl_down(q.y, 1);
    nxt.z = __shfl_down(q.z, 1);
    nxt.w = __shfl_down(q.w, 1);
    if (lane == 63 && jmax >= 64)  // window spans 65 aligned quads
      nxt = *(const vfloat4*)(arow + 64 * 4);
    switch (a) {  // wave-uniform
      case 1:  val.x = q.y; val.y = q.z; val.z = q.w; val.w = nxt.x; break;
      case 2:  val.x = q.z; val.y = q.w; val.z = nxt.x; val.w = nxt.y; break;
      default: val.x = q.w; val.y = nxt.x; val.z = nxt.y; val.w = nxt.z; break;
    }
  }

  const int p = lane * 4;  // output word base within the row
  val.x = (p + 0 < len) ? val.x : 0.0f;
  val.y = (p + 1 < len) ? val.y : 0.0f;
  val.z = (p + 2 < len) ? val.z : 0.0f;
  val.w = (p + 3 < len) ? val.w : 0.0f;

  // out word offset: row*256 + lane*4 == tid*4.
  __builtin_nontemporal_store(val, (vfloat4*)(out + (size_t)tid * 4));
}

// Generic fallback (any max_len): scalar, one block per (b,s,c) row.
__global__ __launch_bounds__(256) void dp_kernel_generic(
    const float* __restrict__ tensor,
    const int* __restrict__ change_points,
    float* __restrict__ out, int max_len) {
  const int c = blockIdx.x;
  const int bs = blockIdx.y;
  const int b = bs >> 6;
  const int s = bs & 63;
  const int start = change_points[b * (DP_S + 1) + s];
  const int len = change_points[b * (DP_S + 1) + s + 1] - start;
  const float* __restrict__ src = tensor + ((size_t)b * DP_C + c) * DP_T;
  float* __restrict__ dst = out + ((size_t)bs * DP_C + c) * (size_t)max_len;
  for (int p = threadIdx.x; p < max_len; p += blockDim.x) {
    float t = 0.0f;
    if (p < len) t = src[start + p];
    dst[p] = t;
  }
}

extern "C" void kernel_launch(void* const* d_in, const int* in_sizes, int n_in,
                              void* d_out, int out_size, void* d_ws, size_t ws_size,
                              hipStream_t stream) {
  const float* tensor = (const float*)d_in[0];
  const int* change_points = (const int*)d_in[1];
  const int max_len = out_size / (DP_B * DP_S * DP_C);
  float* out = (float*)d_out;

  if (max_len == 256) {
    const int nquads = DP_B * DP_S * DP_C * 256 / 4;  // 8.39M
    dp_kernel_flat<<<dim3(nquads / 256), dim3(256), 0, stream>>>(
        tensor, change_points, out);
  } else {
    dp_kernel_generic<<<dim3(DP_C, DP_B * DP_S), dim3(256), 0, stream>>>(
        tensor, change_points, out, max_len);
  }
}

// Round 7
// 185.019 us; speedup vs baseline: 1.0356x; 1.0045x over previous
//
#include <hip/hip_runtime.h>
#include <hip/hip_bf16.h>

// DynamicPatching: B=32, C=64, T=8192, S=64 segments per batch.
// out[b,s,c,p] = (p < end[b,s]-start[b,s]) ? tensor[b,c,start[b,s]+p] : 0
// Output shape (B, S, C, max_length) float32. Measured max_length == 256.
//
// R1: 131k tiny blocks -> 98 us (likely wg-dispatch-rate bound).
// R2: block/(b,s), scalar clamped loads, PLAIN float4 stores -> ~60 us.
// R4/R5/R6: better load structures + NT stores -> 60/57/54 us. Latency model
//     says ~7 us if latency-bound; we're wave-stalled on a memory path
//     saturated at 3.1 TB/s while plain-store fill/copy reach 6.3-6.8 TB/s.
// R7: SINGLE-VARIABLE TEST: R6 structure, drop the non-temporal store hint
//     (suspect: nt bypass path writes at ~half rate on gfx950; both
//     full-BW references use plain stores).

#define DP_B 32
#define DP_C 64
#define DP_T 8192
#define DP_S 64

typedef float vfloat4 __attribute__((ext_vector_type(4)));

// Fast path: L == 256 (one wave == one (b,s,c) row of 64 float4 quads).
__global__ __launch_bounds__(256) void dp_kernel_flat(
    const float* __restrict__ tensor,      // (B, C, T)
    const int* __restrict__ change_points, // (B, S+1)
    float* __restrict__ out) {             // (B, S, C, 256)
  const int tid  = blockIdx.x * 256 + threadIdx.x;
  const int lane = threadIdx.x & 63;
  const int row  = tid >> 6;   // bs*64 + c  (wave-uniform)
  const int c    = row & 63;
  const int bs   = row >> 6;
  const int b    = bs >> 6;
  const int s    = bs & 63;

  // Wave-uniform segment descriptor (compiler scalarizes these loads).
  const int start = change_points[b * (DP_S + 1) + s];
  const int end   = change_points[b * (DP_S + 1) + s + 1];
  const int len   = end - start;
  const int a      = start & 3;   // word misalignment within a quad
  const int base_q = start >> 2;  // first aligned quad
  const int jmax   = ((end - 1) >> 2) - base_q;  // last valid aligned quad

  const float* __restrict__ arow =
      tensor + ((size_t)b * DP_C + c) * DP_T + (size_t)base_q * 4;

  vfloat4 q = {0.0f, 0.0f, 0.0f, 0.0f};
  if (lane <= jmax) q = *(const vfloat4*)(arow + (size_t)lane * 4);

  vfloat4 val;
  if (a == 0) {
    val = q;  // aligned segment: no cross-lane traffic (~25% of rows)
  } else {
    vfloat4 nxt;
    nxt.x = __shfl_down(q.x, 1);
    nxt.y = __shfl_down(q.y, 1);
    nxt.z = __shfl_down(q.z, 1);
    nxt.w = __shfl_down(q.w, 1);
    if (lane == 63 && jmax >= 64)  // window spans 65 aligned quads
      nxt = *(const vfloat4*)(arow + 64 * 4);
    switch (a) {  // wave-uniform
      case 1:  val.x = q.y; val.y = q.z; val.z = q.w; val.w = nxt.x; break;
      case 2:  val.x = q.z; val.y = q.w; val.z = nxt.x; val.w = nxt.y; break;
      default: val.x = q.w; val.y = nxt.x; val.z = nxt.y; val.w = nxt.z; break;
    }
  }

  const int p = lane * 4;  // output word base within the row
  val.x = (p + 0 < len) ? val.x : 0.0f;
  val.y = (p + 1 < len) ? val.y : 0.0f;
  val.z = (p + 2 < len) ? val.z : 0.0f;
  val.w = (p + 3 < len) ? val.w : 0.0f;

  // out word offset: row*256 + lane*4 == tid*4. PLAIN store (R7 change).
  *(vfloat4*)(out + (size_t)tid * 4) = val;
}

// Generic fallback (any max_len): scalar, one block per (b,s,c) row.
__global__ __launch_bounds__(256) void dp_kernel_generic(
    const float* __restrict__ tensor,
    const int* __restrict__ change_points,
    float* __restrict__ out, int max_len) {
  const int c = blockIdx.x;
  const int bs = blockIdx.y;
  const int b = bs >> 6;
  const int s = bs & 63;
  const int start = change_points[b * (DP_S + 1) + s];
  const int len = change_points[b * (DP_S + 1) + s + 1] - start;
  const float* __restrict__ src = tensor + ((size_t)b * DP_C + c) * DP_T;
  float* __restrict__ dst = out + ((size_t)bs * DP_C + c) * (size_t)max_len;
  for (int p = threadIdx.x; p < max_len; p += blockDim.x) {
    float t = 0.0f;
    if (p < len) t = src[start + p];
    dst[p] = t;
  }
}

extern "C" void kernel_launch(void* const* d_in, const int* in_sizes, int n_in,
                              void* d_out, int out_size, void* d_ws, size_t ws_size,
                              hipStream_t stream) {
  const float* tensor = (const float*)d_in[0];
  const int* change_points = (const int*)d_in[1];
  const int max_len = out_size / (DP_B * DP_S * DP_C);
  float* out = (float*)d_out;

  if (max_len == 256) {
    const int nquads = DP_B * DP_S * DP_C * 256 / 4;  // 8.39M
    dp_kernel_flat<<<dim3(nquads / 256), dim3(256), 0, stream>>>(
        tensor, change_points, out);
  } else {
    dp_kernel_generic<<<dim3(DP_C, DP_B * DP_S), dim3(256), 0, stream>>>(
        tensor, change_points, out, max_len);
  }
}